// Round 6
// baseline (305.445 us; speedup 1.0000x reference)
//
#include <hip/hip_runtime.h>
#include <hip/hip_fp16.h>
#include <math.h>

#define NPIX 262144   // 512*512
#define BATCH 4
#define RANK 8
#define CTXD 512
#define OUTF 210

// ---- workspace layout (float offsets) ----
#define XT_OFF   0      // xt[4][210] (840 floats)
#define ACC_OFF  1024   // 8 replicas x 176 accumulators (gram[4][36], S[4][8])
#define REP      8
#define NACC     176
#define WFS_OFF  4096   // byte 16384: __half wfs[NPIX][32] = 16 MiB
#define ZERO_BYTE (ACC_OFF * 4)
#define ZERO_LEN  (REP * NACC * 4)

// ---------------- wave64 sum via DPP (result in lane 63) ---------------------
__device__ __forceinline__ float dpp_sum64(float x) {
  x += __int_as_float(__builtin_amdgcn_update_dpp(0, __float_as_int(x), 0x111, 0xf, 0xf, true)); // row_shr:1
  x += __int_as_float(__builtin_amdgcn_update_dpp(0, __float_as_int(x), 0x112, 0xf, 0xf, true)); // row_shr:2
  x += __int_as_float(__builtin_amdgcn_update_dpp(0, __float_as_int(x), 0x114, 0xf, 0xf, true)); // row_shr:4
  x += __int_as_float(__builtin_amdgcn_update_dpp(0, __float_as_int(x), 0x118, 0xf, 0xf, true)); // row_shr:8
  x += __int_as_float(__builtin_amdgcn_update_dpp(0, __float_as_int(x), 0x142, 0xf, 0xf, true)); // row_bcast:15
  x += __int_as_float(__builtin_amdgcn_update_dpp(0, __float_as_int(x), 0x143, 0xf, 0xf, true)); // row_bcast:31
  return x;
}

// ---------------- threefry2x32 (JAX original scheme, key=(0,42)) -------------
__device__ __forceinline__ void threefry2x32_pair(unsigned int x0, unsigned int x1,
                                                  unsigned int* o0, unsigned int* o1) {
  const unsigned int ks0 = 0u, ks1 = 42u, ks2 = 0x1BD11BF0u;
  x0 += ks0; x1 += ks1;
#define TF_R(rot) { x0 += x1; x1 = (x1 << rot) | (x1 >> (32 - rot)); x1 ^= x0; }
  TF_R(13) TF_R(15) TF_R(26) TF_R(6)
  x0 += ks1; x1 += ks2 + 1u;
  TF_R(17) TF_R(29) TF_R(16) TF_R(24)
  x0 += ks2; x1 += ks0 + 2u;
  TF_R(13) TF_R(15) TF_R(26) TF_R(6)
  x0 += ks0; x1 += ks1 + 3u;
  TF_R(17) TF_R(29) TF_R(16) TF_R(24)
  x0 += ks1; x1 += ks2 + 4u;
  TF_R(13) TF_R(15) TF_R(26) TF_R(6)
  x0 += ks2; x1 += ks0 + 5u;
#undef TF_R
  *o0 = x0; *o1 = x1;
}

// bits -> uniform(-1,1) -> sqrt(2)*erfinv (Giles poly, fast log path).
// Noise enters the output scaled by wr*0.01*std (~1e-10 here), so few-ulp is plenty.
__device__ __forceinline__ float fast_normal(unsigned int bits) {
  unsigned int fb = (bits >> 9) | 0x3f800000u;
  float f = __uint_as_float(fb) - 1.0f;                 // [0,1)
  const float lo = -0.99999994039535522461f;            // nextafter(-1,0) f32
  float u = f * 2.0f + lo;
  u = fmaxf(u, lo);
  float w = -__logf(fmaf(-u, u, 1.0f));                 // -log(1-u^2)
  float q1 = w - 2.5f;
  float p1 = 2.81022636e-08f;
  p1 = fmaf(p1, q1, 3.43273939e-07f);
  p1 = fmaf(p1, q1, -3.5233877e-06f);
  p1 = fmaf(p1, q1, -4.39150654e-06f);
  p1 = fmaf(p1, q1, 0.00021858087f);
  p1 = fmaf(p1, q1, -0.00125372503f);
  p1 = fmaf(p1, q1, -0.00417768164f);
  p1 = fmaf(p1, q1, 0.246640727f);
  p1 = fmaf(p1, q1, 1.50140941f);
  float q2 = sqrtf(w) - 3.0f;
  float p2 = -0.000200214257f;
  p2 = fmaf(p2, q2, 0.000100950558f);
  p2 = fmaf(p2, q2, 0.00134934322f);
  p2 = fmaf(p2, q2, -0.00367342844f);
  p2 = fmaf(p2, q2, 0.00573950773f);
  p2 = fmaf(p2, q2, -0.0076224613f);
  p2 = fmaf(p2, q2, 0.00943887047f);
  p2 = fmaf(p2, q2, 1.00167406f);
  p2 = fmaf(p2, q2, 2.83297682f);
  float pr = (w < 5.0f) ? p1 : p2;
  return 1.4142135623730951f * pr * u;
}

// ---------------- K1: ctx MLP — one 512-dot per wave, 840 waves --------------
__global__ __launch_bounds__(256) void k_ctx(const float* __restrict__ x,
                                             const float* __restrict__ cw,
                                             const float* __restrict__ cb,
                                             float* __restrict__ ws) {
  int lane = threadIdx.x & 63, wv = threadIdx.x >> 6;
  int row = blockIdx.x * 4 + wv;            // 0..839 (grid=210 exactly covers)
  int b = row / OUTF, i = row - b * OUTF;
  const float* wrow = cw + i * CTXD;
  const float* xr = x + b * CTXD;
  float acc = 0.f;
#pragma unroll
  for (int u = 0; u < CTXD; u += 64)
    acc = fmaf(wrow[u + lane], xr[u + lane], acc);
  acc = dpp_sum64(acc);
  if (lane == 63) ws[XT_OFF + row] = acc + cb[i];
}

// ---------------- K2: wf compute + fp16 store, Gram + per-rank sums ----------
// 2 px/thread, float4 (16B) weight loads, 128-thread blocks, 1024 blocks.
__global__ __launch_bounds__(128) void k_wfs(const float* __restrict__ wts,
                                             float* __restrict__ ws) {
  __shared__ float gl[BATCH * 96];
  __shared__ float gred[2][NACC];
  const float* xt = ws + XT_OFF;
  __half* wfs16 = (__half*)((char*)ws + WFS_OFF * 4);
  int t = threadIdx.x;
  // per-block gating recompute (trivial): g = xt[:105]*tanh(xt[105:])
  for (int i = t; i < BATCH * 96; i += 128) {
    int b = i / 96, j = i - b * 96;
    gl[i] = xt[b * OUTF + j] * tanhf(xt[b * OUTF + 105 + j]);
  }
  __syncthreads();

  int tp = blockIdx.x * 128 + t;            // 0..131071 (2 pixels each)
  int p0 = tp << 1;
  const float4* w4 = (const float4*)wts;    // float4 = 2 complex px; page = 2^17 float4
  float wf[BATCH][RANK][2];
#pragma unroll
  for (int k = 0; k < RANK; ++k) {
    // ld[s][comp] = {px0.re, px0.im, px1.re, px1.im}
    float4 ld[2][2];
#pragma unroll
    for (int s = 0; s < 2; ++s)
#pragma unroll
      for (int comp = 0; comp < 2; ++comp)
        ld[s][comp] = w4[((k * 4 + s * 2 + comp) << 17) + tp];
#pragma unroll
    for (int b = 0; b < BATCH; ++b) {
      const float* gb = gl + b * 96 + 12 * k;
      float zr[2][2], zi[2][2];   // [comp][pixel]
#pragma unroll
      for (int comp = 0; comp < 2; ++comp) {
        float c0 = gb[2 * comp] + 0.5f;
        float c1 = gb[2 * comp + 1];
        float b0 = gb[4 + 2 * comp];
        float b1 = gb[5 + 2 * comp];
        float s0 = gb[8 + 2 * comp] + 1.0f;
        float s1 = gb[9 + 2 * comp];
        float4 W0 = ld[0][comp], W1 = ld[1][comp];
#pragma unroll
        for (int j = 0; j < 2; ++j) {
          float w0r = j ? W0.z : W0.x;
          float w0i = j ? W0.w : W0.y;
          float w1r = j ? W1.z : W1.x;
          float w1i = j ? W1.w : W1.y;
          float dr = w1r - w0r, di = w1i - w0i;
          float lr = w0r + c0 * dr - c1 * di;
          float li = w0i + c0 * di + c1 * dr;
          zr[comp][j] = b0 + lr * s0 - li * s1;
          zi[comp][j] = b1 + lr * s1 + li * s0;
        }
      }
#pragma unroll
      for (int j = 0; j < 2; ++j) {
        float d2 = zr[1][j] * zr[1][j] + zi[1][j] * zi[1][j];
        float dn = sqrtf(fmaxf(d2, 1e-12f));
        float w = (zr[0][j] * zr[1][j] + zi[0][j] * zi[1][j]) / dn;
        if (fabsf(w) < 1e-12f) w = (w > 0.f) ? 1e-12f : ((w < 0.f) ? -1e-12f : 0.f);
        wf[b][k][j] = w;
      }
    }
  }
  // store: per pixel, 32 halves (b*8+k order) = 64 B contiguous
#pragma unroll
  for (int j = 0; j < 2; ++j) {
    union { __half h[32]; float4 f4[4]; } pk;
#pragma unroll
    for (int b = 0; b < BATCH; ++b)
#pragma unroll
      for (int k = 0; k < RANK; ++k)
        pk.h[b * 8 + k] = __float2half(wf[b][k][j]);
    float4* wp = (float4*)(wfs16 + (size_t)(p0 + j) * 32);
#pragma unroll
    for (int i = 0; i < 4; ++i) wp[i] = pk.f4[i];
  }
  // reduce gram[4][36] (upper-tri incl diag) + S[4][8] — exact f32 values
  int lane = t & 63, wv = t >> 6;
#pragma unroll
  for (int b = 0; b < BATCH; ++b) {
    int idx = b * 36;
#pragma unroll
    for (int r = 0; r < RANK; ++r)
#pragma unroll
      for (int s = r; s < RANK; ++s, ++idx) {
        float pr = dpp_sum64(wf[b][r][0] * wf[b][s][0] + wf[b][r][1] * wf[b][s][1]);
        if (lane == 63) gred[wv][idx] = pr;
      }
  }
#pragma unroll
  for (int b = 0; b < BATCH; ++b)
#pragma unroll
    for (int k = 0; k < RANK; ++k) {
      float pr = dpp_sum64(wf[b][k][0] + wf[b][k][1]);
      if (lane == 63) gred[wv][144 + b * 8 + k] = pr;
    }
  __syncthreads();
  // NOTE: block has 128 threads but NACC=176 — must stride (R5 bug: poison in 128..175)
  for (int i = t; i < NACC; i += 128) {
    float s = gred[0][i] + gred[1][i];
    // 8-way replicated accumulators: same-address contention /8
    atomicAdd(ws + ACC_OFF + (blockIdx.x & (REP - 1)) * NACC + i, s);
  }
}

// ---------------- K3: analytic stats + output + noise ------------------------
__global__ __launch_bounds__(256) void k_out(const float* __restrict__ ws,
                                             float* __restrict__ out) {
  const float* xt = ws + XT_OFF;
  const __half* wfs16 = (const __half*)((const char*)ws + WFS_OFF * 4);
  __shared__ float G[NACC];                  // [0:144) gram, [144:176) S
  __shared__ float n1[32], Ml[256], vv[32], scl[32], ca[4], wrl[BATCH][9];
  __shared__ float in2[32], mnv[32], sdv[32];
  int t = threadIdx.x;
  if (t < NACC) {
    float s = 0.f;
#pragma unroll
    for (int rep = 0; rep < REP; ++rep) s += ws[ACC_OFF + rep * NACC + t];
    G[t] = s;
  }
  if (t >= 192 && t < 192 + BATCH) {         // wr softmax (per-batch thread)
    int b = t - 192;
    float raw[9];
#pragma unroll
    for (int j = 0; j < 9; ++j)
      raw[j] = xt[b * OUTF + 96 + j] * tanhf(xt[b * OUTF + 201 + j]);
    raw[8] += 0.35355339059327373f;          // 1/sqrt(8)
    double ss = 0.0;
    for (int j = 0; j < 9; ++j) ss += (double)raw[j] * (double)raw[j];
    float n = fmaxf((float)sqrt(ss), 1e-12f);
    float y[9]; float m = -1e30f;
    for (int j = 0; j < 9; ++j) { y[j] = raw[j] / n; m = fmaxf(m, y[j]); }
    float e[9]; double se = 0.0;
    for (int j = 0; j < 9; ++j) { e[j] = expf(y[j] - m); se += (double)e[j]; }
    for (int j = 0; j < 9; ++j) wrl[b][j] = e[j] / (float)se;
  }
  __syncthreads();
  if (t < 32) {
    int b = t >> 3, k = t & 7;
    int di = k * 8 - (k * (k - 1)) / 2;
    n1[t] = fmaxf(sqrtf(G[b * 36 + di]), 1e-12f);
  }
  __syncthreads();
  {
    int b = t >> 6, k = (t >> 3) & 7, s = t & 7;
    float m;
    if (k == s) {
      m = 1.0f / n1[b * 8 + k];
    } else {
      int r0 = k < s ? k : s, s0 = k < s ? s : k;
      int gi = r0 * 8 - (r0 * (r0 - 1)) / 2 + (s0 - r0);
      float simv = G[b * 36 + gi] / (n1[b * 8 + k] * n1[b * 8 + s]);
      m = -0.0050507627227610544f * simv / n1[b * 8 + s];  // (0.1/sqrt(8))/7
    }
    Ml[t] = m;
  }
  __syncthreads();
  if (t < 32) {
    int b = t >> 3, k = t & 7;
    // sum = M.S ; sumsq = (M G M^T)_kk — exact linear algebra of the 2nd pass
    float sum = 0.f, sq = 0.f;
#pragma unroll
    for (int s = 0; s < 8; ++s) {
      float ms = Ml[b * 64 + k * 8 + s];
      sum = fmaf(ms, G[144 + b * 8 + s], sum);
#pragma unroll
      for (int u = 0; u < 8; ++u) {
        int r0 = s < u ? s : u, s0 = s < u ? u : s;
        int gi = r0 * 8 - (r0 * (r0 - 1)) / 2 + (s0 - r0);
        sq = fmaf(ms * Ml[b * 64 + k * 8 + u], G[b * 36 + gi], sq);
      }
    }
    float n2 = fmaxf(sqrtf(fmaxf(sq, 0.f)), 1e-12f);
    float mean = sum / n2 * (1.0f / NPIX);
    float sy2 = sq / (n2 * n2);
    float var = (sy2 - (float)NPIX * mean * mean) * (1.0f / (float)(NPIX - 1));
    var = fmaxf(var, 0.f);
    float sd = fmaxf(sqrtf(var), 1e-12f);
    in2[t] = 1.f / n2; mnv[t] = mean; sdv[t] = sd;
  }
  __syncthreads();
  if (t < 32) {
    int b = t >> 3, s = t & 7;
    float acc = 0.f;
#pragma unroll
    for (int k = 0; k < 8; ++k)
      acc += wrl[b][k] * Ml[b * 64 + k * 8 + s] * in2[b * 8 + k];
    vv[t] = acc;
    scl[t] = wrl[b][s] * 0.01f * sdv[t];
  }
  if (t < BATCH) {
    float a = 0.f;
#pragma unroll
    for (int k = 0; k < 8; ++k) a += wrl[t][k] * 0.01f * mnv[t * 8 + k];
    ca[t] = a;
  }
  __syncthreads();

  int p = blockIdx.x * 256 + t;
  union { __half h[32]; float4 f4[4]; } pk;
  {
    const float4* rp = (const float4*)(wfs16 + (size_t)p * 32);
#pragma unroll
    for (int i = 0; i < 4; ++i) pk.f4[i] = rp[i];
  }
  float o[4];
#pragma unroll
  for (int b = 0; b < 4; ++b) {
    float acc = ca[b];
#pragma unroll
    for (int s = 0; s < 8; ++s)
      acc = fmaf(vv[b * 8 + s], __half2float(pk.h[b * 8 + s]), acc);
    o[b] = acc;
  }
  // noise: flat j=(b*8+k)*NPIX+p over 2^23 elems; (j, j+2^22) share a threefry block
#pragma unroll
  for (int bk = 0; bk < 16; ++bk) {
    unsigned int i = ((unsigned int)bk << 18) + (unsigned int)p;
    unsigned int r0, r1;
    threefry2x32_pair(i, i + 0x400000u, &r0, &r1);
    int b2 = bk >> 3, k = bk & 7;
    o[b2]     += scl[b2 * 8 + k]       * fast_normal(r0);
    o[b2 + 2] += scl[(b2 + 2) * 8 + k] * fast_normal(r1);
  }
#pragma unroll
  for (int b = 0; b < 4; ++b) out[(b << 18) + p] = o[b];
}

extern "C" void kernel_launch(void* const* d_in, const int* in_sizes, int n_in,
                              void* d_out, int out_size, void* d_ws, size_t ws_size,
                              hipStream_t stream) {
  const float* x   = (const float*)d_in[0];
  const float* cw  = (const float*)d_in[1];
  const float* cb  = (const float*)d_in[2];
  const float* wts = (const float*)d_in[3];
  float* out = (float*)d_out;
  float* ws  = (float*)d_ws;

  hipMemsetAsync((char*)d_ws + ZERO_BYTE, 0, ZERO_LEN, stream);

  k_ctx <<<210,  256, 0, stream>>>(x, cw, cb, ws);
  k_wfs <<<1024, 128, 0, stream>>>(wts, ws);
  k_out <<<1024, 256, 0, stream>>>(ws, out);
}

// Round 7
// 151.256 us; speedup vs baseline: 2.0194x; 2.0194x over previous
//
#include <hip/hip_runtime.h>
#include <hip/hip_fp16.h>
#include <math.h>

#define NPIX 262144   // 512*512
#define BATCH 4
#define RANK 8
#define CTXD 512
#define OUTF 210

// ---- workspace layout (float offsets) ----
#define XT_OFF   0      // xt[4][210] (840 floats)
#define ACC_OFF  1024   // 8 replicas x 176 accumulators (gram[4][36], S[4][8])
#define REP      8
#define NACC     176
#define WFS_OFF  4096   // byte 16384: __half wfs[32][NPIX] rank-major = 16 MiB
#define ZERO_BYTE (ACC_OFF * 4)
#define ZERO_LEN  (REP * NACC * 4)

// ---------------- wave64 sum via DPP (result in lane 63) ---------------------
__device__ __forceinline__ float dpp_sum64(float x) {
  x += __int_as_float(__builtin_amdgcn_update_dpp(0, __float_as_int(x), 0x111, 0xf, 0xf, true)); // row_shr:1
  x += __int_as_float(__builtin_amdgcn_update_dpp(0, __float_as_int(x), 0x112, 0xf, 0xf, true)); // row_shr:2
  x += __int_as_float(__builtin_amdgcn_update_dpp(0, __float_as_int(x), 0x114, 0xf, 0xf, true)); // row_shr:4
  x += __int_as_float(__builtin_amdgcn_update_dpp(0, __float_as_int(x), 0x118, 0xf, 0xf, true)); // row_shr:8
  x += __int_as_float(__builtin_amdgcn_update_dpp(0, __float_as_int(x), 0x142, 0xf, 0xf, true)); // row_bcast:15
  x += __int_as_float(__builtin_amdgcn_update_dpp(0, __float_as_int(x), 0x143, 0xf, 0xf, true)); // row_bcast:31
  return x;
}

// ---------------- threefry2x32 (JAX original scheme, key=(0,42)) -------------
__device__ __forceinline__ void threefry2x32_pair(unsigned int x0, unsigned int x1,
                                                  unsigned int* o0, unsigned int* o1) {
  const unsigned int ks0 = 0u, ks1 = 42u, ks2 = 0x1BD11BF0u;
  x0 += ks0; x1 += ks1;
#define TF_R(rot) { x0 += x1; x1 = (x1 << rot) | (x1 >> (32 - rot)); x1 ^= x0; }
  TF_R(13) TF_R(15) TF_R(26) TF_R(6)
  x0 += ks1; x1 += ks2 + 1u;
  TF_R(17) TF_R(29) TF_R(16) TF_R(24)
  x0 += ks2; x1 += ks0 + 2u;
  TF_R(13) TF_R(15) TF_R(26) TF_R(6)
  x0 += ks0; x1 += ks1 + 3u;
  TF_R(17) TF_R(29) TF_R(16) TF_R(24)
  x0 += ks1; x1 += ks2 + 4u;
  TF_R(13) TF_R(15) TF_R(26) TF_R(6)
  x0 += ks2; x1 += ks0 + 5u;
#undef TF_R
  *o0 = x0; *o1 = x1;
}

// bits -> uniform(-1,1) -> sqrt(2)*erfinv (Giles poly, fast log path).
// Noise enters the output scaled by wr*0.01*std (~1e-10 here), so few-ulp is plenty.
__device__ __forceinline__ float fast_normal(unsigned int bits) {
  unsigned int fb = (bits >> 9) | 0x3f800000u;
  float f = __uint_as_float(fb) - 1.0f;                 // [0,1)
  const float lo = -0.99999994039535522461f;            // nextafter(-1,0) f32
  float u = f * 2.0f + lo;
  u = fmaxf(u, lo);
  float w = -__logf(fmaf(-u, u, 1.0f));                 // -log(1-u^2)
  float q1 = w - 2.5f;
  float p1 = 2.81022636e-08f;
  p1 = fmaf(p1, q1, 3.43273939e-07f);
  p1 = fmaf(p1, q1, -3.5233877e-06f);
  p1 = fmaf(p1, q1, -4.39150654e-06f);
  p1 = fmaf(p1, q1, 0.00021858087f);
  p1 = fmaf(p1, q1, -0.00125372503f);
  p1 = fmaf(p1, q1, -0.00417768164f);
  p1 = fmaf(p1, q1, 0.246640727f);
  p1 = fmaf(p1, q1, 1.50140941f);
  float q2 = sqrtf(w) - 3.0f;
  float p2 = -0.000200214257f;
  p2 = fmaf(p2, q2, 0.000100950558f);
  p2 = fmaf(p2, q2, 0.00134934322f);
  p2 = fmaf(p2, q2, -0.00367342844f);
  p2 = fmaf(p2, q2, 0.00573950773f);
  p2 = fmaf(p2, q2, -0.0076224613f);
  p2 = fmaf(p2, q2, 0.00943887047f);
  p2 = fmaf(p2, q2, 1.00167406f);
  p2 = fmaf(p2, q2, 2.83297682f);
  float pr = (w < 5.0f) ? p1 : p2;
  return 1.4142135623730951f * pr * u;
}

// ---------------- K1: ctx MLP — one 512-dot per wave, 840 waves --------------
__global__ __launch_bounds__(256) void k_ctx(const float* __restrict__ x,
                                             const float* __restrict__ cw,
                                             const float* __restrict__ cb,
                                             float* __restrict__ ws) {
  int lane = threadIdx.x & 63, wv = threadIdx.x >> 6;
  int row = blockIdx.x * 4 + wv;            // 0..839 (grid=210 exactly covers)
  int b = row / OUTF, i = row - b * OUTF;
  const float* wrow = cw + i * CTXD;
  const float* xr = x + b * CTXD;
  float acc = 0.f;
#pragma unroll
  for (int u = 0; u < CTXD; u += 64)
    acc = fmaf(wrow[u + lane], xr[u + lane], acc);
  acc = dpp_sum64(acc);
  if (lane == 63) ws[XT_OFF + row] = acc + cb[i];
}

// ---------------- K2: wf compute + fp16 store, Gram + per-rank sums ----------
// 1 px/thread, 256-thread blocks, 1024 blocks — R4's proven structure; stores
// streamed inside the loop (NO end-of-kernel packing union: that spilled in R6,
// VGPR 256 + 64MB scratch writes).
__global__ __launch_bounds__(256) void k_wfs(const float* __restrict__ wts,
                                             float* __restrict__ ws) {
  __shared__ float gl[BATCH * 96];
  __shared__ float gred[4][NACC];
  const float* xt = ws + XT_OFF;
  __half* wfs16 = (__half*)((char*)ws + WFS_OFF * 4);
  int t = threadIdx.x;
  // per-block gating recompute (trivial): g = xt[:105]*tanh(xt[105:])
  for (int i = t; i < BATCH * 96; i += 256) {
    int b = i / 96, j = i - b * 96;
    gl[i] = xt[b * OUTF + j] * tanhf(xt[b * OUTF + 105 + j]);
  }
  __syncthreads();

  int p = blockIdx.x * 256 + t;             // 1 pixel per thread
  const float2* w2 = (const float2*)wts;
  float wf[BATCH][RANK];
#pragma unroll
  for (int k = 0; k < RANK; ++k) {
    // layout: page (k*4 + s*2 + comp), complex float2 per pixel
    float2 W0c0 = w2[((k * 4 + 0) << 18) + p];
    float2 W0c1 = w2[((k * 4 + 1) << 18) + p];
    float2 W1c0 = w2[((k * 4 + 2) << 18) + p];
    float2 W1c1 = w2[((k * 4 + 3) << 18) + p];
#pragma unroll
    for (int b = 0; b < BATCH; ++b) {
      const float* gb = gl + b * 96 + 12 * k;
      float zr0, zi0, zr1, zi1;
      {
        float c0 = gb[0] + 0.5f, c1 = gb[1], b0 = gb[4], b1 = gb[5];
        float s0 = gb[8] + 1.0f, s1 = gb[9];
        float dr = W1c0.x - W0c0.x, di = W1c0.y - W0c0.y;
        float lr = W0c0.x + c0 * dr - c1 * di;
        float li = W0c0.y + c0 * di + c1 * dr;
        zr0 = b0 + lr * s0 - li * s1;
        zi0 = b1 + lr * s1 + li * s0;
      }
      {
        float c0 = gb[2] + 0.5f, c1 = gb[3], b0 = gb[6], b1 = gb[7];
        float s0 = gb[10] + 1.0f, s1 = gb[11];
        float dr = W1c1.x - W0c1.x, di = W1c1.y - W0c1.y;
        float lr = W0c1.x + c0 * dr - c1 * di;
        float li = W0c1.y + c0 * di + c1 * dr;
        zr1 = b0 + lr * s0 - li * s1;
        zi1 = b1 + lr * s1 + li * s0;
      }
      float d2 = zr1 * zr1 + zi1 * zi1;
      float dn = sqrtf(fmaxf(d2, 1e-12f));
      float w = (zr0 * zr1 + zi0 * zi1) / dn;
      if (fabsf(w) < 1e-12f) w = (w > 0.f) ? 1e-12f : ((w < 0.f) ? -1e-12f : 0.f);
      wf[b][k] = w;
      wfs16[((b * RANK + k) << 18) + p] = __float2half(w);  // streamed, coalesced
    }
  }
  // reduce gram[4][36] (upper-tri incl diag) + S[4][8] — exact f32 values
  int lane = t & 63, wv = t >> 6;
#pragma unroll
  for (int b = 0; b < BATCH; ++b) {
    int idx = b * 36;
#pragma unroll
    for (int r = 0; r < RANK; ++r)
#pragma unroll
      for (int s = r; s < RANK; ++s, ++idx) {
        float pr = dpp_sum64(wf[b][r] * wf[b][s]);
        if (lane == 63) gred[wv][idx] = pr;
      }
  }
#pragma unroll
  for (int b = 0; b < BATCH; ++b)
#pragma unroll
    for (int k = 0; k < RANK; ++k) {
      float pr = dpp_sum64(wf[b][k]);
      if (lane == 63) gred[wv][144 + b * 8 + k] = pr;
    }
  __syncthreads();
  if (t < NACC) {
    float s = gred[0][t] + gred[1][t] + gred[2][t] + gred[3][t];
    // 8-way replicated accumulators: same-address contention /8
    atomicAdd(ws + ACC_OFF + (blockIdx.x & (REP - 1)) * NACC + t, s);
  }
}

// ---------------- K3: analytic stats + output + noise ------------------------
__global__ __launch_bounds__(256) void k_out(const float* __restrict__ ws,
                                             float* __restrict__ out) {
  const float* xt = ws + XT_OFF;
  const __half* wfs16 = (const __half*)((const char*)ws + WFS_OFF * 4);
  __shared__ float G[NACC];                  // [0:144) gram, [144:176) S
  __shared__ float n1[32], Ml[256], vv[32], scl[32], ca[4], wrl[BATCH][9];
  __shared__ float in2[32], mnv[32], sdv[32];
  int t = threadIdx.x;
  if (t < NACC) {
    float s = 0.f;
#pragma unroll
    for (int rep = 0; rep < REP; ++rep) s += ws[ACC_OFF + rep * NACC + t];
    G[t] = s;
  }
  if (t >= 192 && t < 192 + BATCH) {         // wr softmax (per-batch thread)
    int b = t - 192;
    float raw[9];
#pragma unroll
    for (int j = 0; j < 9; ++j)
      raw[j] = xt[b * OUTF + 96 + j] * tanhf(xt[b * OUTF + 201 + j]);
    raw[8] += 0.35355339059327373f;          // 1/sqrt(8)
    double ss = 0.0;
    for (int j = 0; j < 9; ++j) ss += (double)raw[j] * (double)raw[j];
    float n = fmaxf((float)sqrt(ss), 1e-12f);
    float y[9]; float m = -1e30f;
    for (int j = 0; j < 9; ++j) { y[j] = raw[j] / n; m = fmaxf(m, y[j]); }
    float e[9]; double se = 0.0;
    for (int j = 0; j < 9; ++j) { e[j] = expf(y[j] - m); se += (double)e[j]; }
    for (int j = 0; j < 9; ++j) wrl[b][j] = e[j] / (float)se;
  }
  __syncthreads();
  if (t < 32) {
    int b = t >> 3, k = t & 7;
    int di = k * 8 - (k * (k - 1)) / 2;
    n1[t] = fmaxf(sqrtf(G[b * 36 + di]), 1e-12f);
  }
  __syncthreads();
  {
    int b = t >> 6, k = (t >> 3) & 7, s = t & 7;
    float m;
    if (k == s) {
      m = 1.0f / n1[b * 8 + k];
    } else {
      int r0 = k < s ? k : s, s0 = k < s ? s : k;
      int gi = r0 * 8 - (r0 * (r0 - 1)) / 2 + (s0 - r0);
      float simv = G[b * 36 + gi] / (n1[b * 8 + k] * n1[b * 8 + s]);
      m = -0.0050507627227610544f * simv / n1[b * 8 + s];  // (0.1/sqrt(8))/7
    }
    Ml[t] = m;
  }
  __syncthreads();
  if (t < 32) {
    int b = t >> 3, k = t & 7;
    // sum = M.S ; sumsq = (M G M^T)_kk — exact linear algebra of the 2nd pass
    float sum = 0.f, sq = 0.f;
#pragma unroll
    for (int s = 0; s < 8; ++s) {
      float ms = Ml[b * 64 + k * 8 + s];
      sum = fmaf(ms, G[144 + b * 8 + s], sum);
#pragma unroll
      for (int u = 0; u < 8; ++u) {
        int r0 = s < u ? s : u, s0 = s < u ? u : s;
        int gi = r0 * 8 - (r0 * (r0 - 1)) / 2 + (s0 - r0);
        sq = fmaf(ms * Ml[b * 64 + k * 8 + u], G[b * 36 + gi], sq);
      }
    }
    float n2 = fmaxf(sqrtf(fmaxf(sq, 0.f)), 1e-12f);
    float mean = sum / n2 * (1.0f / NPIX);
    float sy2 = sq / (n2 * n2);
    float var = (sy2 - (float)NPIX * mean * mean) * (1.0f / (float)(NPIX - 1));
    var = fmaxf(var, 0.f);
    float sd = fmaxf(sqrtf(var), 1e-12f);
    in2[t] = 1.f / n2; mnv[t] = mean; sdv[t] = sd;
  }
  __syncthreads();
  if (t < 32) {
    int b = t >> 3, s = t & 7;
    float acc = 0.f;
#pragma unroll
    for (int k = 0; k < 8; ++k)
      acc += wrl[b][k] * Ml[b * 64 + k * 8 + s] * in2[b * 8 + k];
    vv[t] = acc;
    scl[t] = wrl[b][s] * 0.01f * sdv[t];
  }
  if (t < BATCH) {
    float a = 0.f;
#pragma unroll
    for (int k = 0; k < 8; ++k) a += wrl[t][k] * 0.01f * mnv[t * 8 + k];
    ca[t] = a;
  }
  __syncthreads();

  int p = blockIdx.x * 256 + t;
  float o[4];
#pragma unroll
  for (int b = 0; b < 4; ++b) {
    float acc = ca[b];
#pragma unroll
    for (int s = 0; s < 8; ++s)
      acc = fmaf(vv[b * 8 + s], __half2float(wfs16[((b * RANK + s) << 18) + p]), acc);
    o[b] = acc;
  }
  // noise: flat j=(b*8+k)*NPIX+p over 2^23 elems; (j, j+2^22) share a threefry block
#pragma unroll
  for (int bk = 0; bk < 16; ++bk) {
    unsigned int i = ((unsigned int)bk << 18) + (unsigned int)p;
    unsigned int r0, r1;
    threefry2x32_pair(i, i + 0x400000u, &r0, &r1);
    int b2 = bk >> 3, k = bk & 7;
    o[b2]     += scl[b2 * 8 + k]       * fast_normal(r0);
    o[b2 + 2] += scl[(b2 + 2) * 8 + k] * fast_normal(r1);
  }
#pragma unroll
  for (int b = 0; b < 4; ++b) out[(b << 18) + p] = o[b];
}

extern "C" void kernel_launch(void* const* d_in, const int* in_sizes, int n_in,
                              void* d_out, int out_size, void* d_ws, size_t ws_size,
                              hipStream_t stream) {
  const float* x   = (const float*)d_in[0];
  const float* cw  = (const float*)d_in[1];
  const float* cb  = (const float*)d_in[2];
  const float* wts = (const float*)d_in[3];
  float* out = (float*)d_out;
  float* ws  = (float*)d_ws;

  hipMemsetAsync((char*)d_ws + ZERO_BYTE, 0, ZERO_LEN, stream);

  k_ctx <<<210,  256, 0, stream>>>(x, cw, cb, ws);
  k_wfs <<<1024, 256, 0, stream>>>(wts, ws);
  k_out <<<1024, 256, 0, stream>>>(ws, out);
}

// Round 8
// 144.199 us; speedup vs baseline: 2.1182x; 1.0489x over previous
//
#include <hip/hip_runtime.h>
#include <hip/hip_fp16.h>
#include <math.h>

#define NPIX 262144   // 512*512
#define BATCH 4
#define RANK 8
#define CTXD 512
#define OUTF 210

// ---- workspace layout (float offsets) ----
#define XT_OFF   0      // xt[4][210] (840 floats)
#define ACC_OFF  1024   // 8 replicas x 176 accumulators (gram[4][36], S[4][8])
#define REP      8
#define NACC     176
#define WFS_OFF  4096   // byte 16384: __half wfs[32][NPIX] rank-major = 16 MiB
#define ZERO_BYTE (ACC_OFF * 4)
#define ZERO_LEN  (REP * NACC * 4)

// ---------------- wave64 sum via DPP (result in lane 63) ---------------------
__device__ __forceinline__ float dpp_sum64(float x) {
  x += __int_as_float(__builtin_amdgcn_update_dpp(0, __float_as_int(x), 0x111, 0xf, 0xf, true)); // row_shr:1
  x += __int_as_float(__builtin_amdgcn_update_dpp(0, __float_as_int(x), 0x112, 0xf, 0xf, true)); // row_shr:2
  x += __int_as_float(__builtin_amdgcn_update_dpp(0, __float_as_int(x), 0x114, 0xf, 0xf, true)); // row_shr:4
  x += __int_as_float(__builtin_amdgcn_update_dpp(0, __float_as_int(x), 0x118, 0xf, 0xf, true)); // row_shr:8
  x += __int_as_float(__builtin_amdgcn_update_dpp(0, __float_as_int(x), 0x142, 0xf, 0xf, true)); // row_bcast:15
  x += __int_as_float(__builtin_amdgcn_update_dpp(0, __float_as_int(x), 0x143, 0xf, 0xf, true)); // row_bcast:31
  return x;
}

// ---------------- threefry2x32 (JAX original scheme, key=(0,42)) -------------
__device__ __forceinline__ void threefry2x32_pair(unsigned int x0, unsigned int x1,
                                                  unsigned int* o0, unsigned int* o1) {
  const unsigned int ks0 = 0u, ks1 = 42u, ks2 = 0x1BD11BF0u;
  x0 += ks0; x1 += ks1;
#define TF_R(rot) { x0 += x1; x1 = (x1 << rot) | (x1 >> (32 - rot)); x1 ^= x0; }
  TF_R(13) TF_R(15) TF_R(26) TF_R(6)
  x0 += ks1; x1 += ks2 + 1u;
  TF_R(17) TF_R(29) TF_R(16) TF_R(24)
  x0 += ks2; x1 += ks0 + 2u;
  TF_R(13) TF_R(15) TF_R(26) TF_R(6)
  x0 += ks0; x1 += ks1 + 3u;
  TF_R(17) TF_R(29) TF_R(16) TF_R(24)
  x0 += ks1; x1 += ks2 + 4u;
  TF_R(13) TF_R(15) TF_R(26) TF_R(6)
  x0 += ks2; x1 += ks0 + 5u;
#undef TF_R
  *o0 = x0; *o1 = x1;
}

// bits -> uniform(-1,1) -> sqrt(2)*erfinv (Giles poly, fast log path).
// Noise enters the output scaled by wr*0.01*std (~1e-10 here), so few-ulp is plenty.
__device__ __forceinline__ float fast_normal(unsigned int bits) {
  unsigned int fb = (bits >> 9) | 0x3f800000u;
  float f = __uint_as_float(fb) - 1.0f;                 // [0,1)
  const float lo = -0.99999994039535522461f;            // nextafter(-1,0) f32
  float u = f * 2.0f + lo;
  u = fmaxf(u, lo);
  float w = -__logf(fmaf(-u, u, 1.0f));                 // -log(1-u^2)
  float q1 = w - 2.5f;
  float p1 = 2.81022636e-08f;
  p1 = fmaf(p1, q1, 3.43273939e-07f);
  p1 = fmaf(p1, q1, -3.5233877e-06f);
  p1 = fmaf(p1, q1, -4.39150654e-06f);
  p1 = fmaf(p1, q1, 0.00021858087f);
  p1 = fmaf(p1, q1, -0.00125372503f);
  p1 = fmaf(p1, q1, -0.00417768164f);
  p1 = fmaf(p1, q1, 0.246640727f);
  p1 = fmaf(p1, q1, 1.50140941f);
  float q2 = sqrtf(w) - 3.0f;
  float p2 = -0.000200214257f;
  p2 = fmaf(p2, q2, 0.000100950558f);
  p2 = fmaf(p2, q2, 0.00134934322f);
  p2 = fmaf(p2, q2, -0.00367342844f);
  p2 = fmaf(p2, q2, 0.00573950773f);
  p2 = fmaf(p2, q2, -0.0076224613f);
  p2 = fmaf(p2, q2, 0.00943887047f);
  p2 = fmaf(p2, q2, 1.00167406f);
  p2 = fmaf(p2, q2, 2.83297682f);
  float pr = (w < 5.0f) ? p1 : p2;
  return 1.4142135623730951f * pr * u;
}

// ---------------- K1: ctx MLP — one 512-dot per wave, 840 waves --------------
__global__ __launch_bounds__(256) void k_ctx(const float* __restrict__ x,
                                             const float* __restrict__ cw,
                                             const float* __restrict__ cb,
                                             float* __restrict__ ws) {
  int lane = threadIdx.x & 63, wv = threadIdx.x >> 6;
  int row = blockIdx.x * 4 + wv;            // 0..839 (grid=210 exactly covers)
  int b = row / OUTF, i = row - b * OUTF;
  const float* wrow = cw + i * CTXD;
  const float* xr = x + b * CTXD;
  float acc = 0.f;
#pragma unroll
  for (int u = 0; u < CTXD; u += 64)
    acc = fmaf(wrow[u + lane], xr[u + lane], acc);
  acc = dpp_sum64(acc);
  if (lane == 63) ws[XT_OFF + row] = acc + cb[i];
}

// ---------------- K2: wf compute + fp16 store, Gram + per-rank sums ----------
// Folded modulation: z = bias + A*w0 + B*w1 (complex), A=s(1-c), B=s*c computed
// once per (b,k) in the block prologue -> LDS float4s (3 x ds_read_b128 per
// (k,b) instead of 12 ds_read_b32; 16 FMA instead of ~16 mixed ops + rsq).
__global__ __launch_bounds__(256) void k_wfs(const float* __restrict__ wts,
                                             float* __restrict__ ws) {
  __shared__ float4 mods[32][3];   // [b*8+k][0]=A0,B0  [1]=A1,B1  [2]=biases
  __shared__ float gred[4][NACC];
  const float* xt = ws + XT_OFF;
  __half* wfs16 = (__half*)((char*)ws + WFS_OFF * 4);
  int t = threadIdx.x;

  if (t < 96) {
    int bk = t / 3, part = t - bk * 3;
    int b = bk >> 3, k = bk & 7;
    const float* xb = xt + b * OUTF + 12 * k;
#define GATE(j) (xb[j] * tanhf(xb[105 + (j)]))
    float4 r;
    if (part < 2) {
      float c0 = GATE(2 * part) + 0.5f;
      float c1 = GATE(2 * part + 1);
      float s0 = GATE(8 + 2 * part) + 1.0f;
      float s1 = GATE(9 + 2 * part);
      float omc = 1.0f - c0;
      r.x = s0 * omc + s1 * c1;   // A_r
      r.y = s1 * omc - s0 * c1;   // A_i
      r.z = s0 * c0 - s1 * c1;    // B_r
      r.w = s1 * c0 + s0 * c1;    // B_i
    } else {
      r.x = GATE(4); r.y = GATE(5); r.z = GATE(6); r.w = GATE(7);
    }
#undef GATE
    mods[bk][part] = r;
  }
  __syncthreads();

  int p = blockIdx.x * 256 + t;             // 1 pixel per thread
  const float2* w2 = (const float2*)wts;
  float wf[BATCH][RANK];
#pragma unroll
  for (int k = 0; k < RANK; ++k) {
    // layout: page (k*4 + lerp*2 + comp), complex float2 per pixel
    float2 W0c0 = w2[((k * 4 + 0) << 18) + p];
    float2 W0c1 = w2[((k * 4 + 1) << 18) + p];
    float2 W1c0 = w2[((k * 4 + 2) << 18) + p];
    float2 W1c1 = w2[((k * 4 + 3) << 18) + p];
#pragma unroll
    for (int b = 0; b < BATCH; ++b) {
      float4 P  = mods[b * 8 + k][0];
      float4 Q  = mods[b * 8 + k][1];
      float4 Bb = mods[b * 8 + k][2];
      float zr0 = fmaf(P.x, W0c0.x, fmaf(-P.y, W0c0.y, fmaf(P.z, W1c0.x, fmaf(-P.w, W1c0.y, Bb.x))));
      float zi0 = fmaf(P.y, W0c0.x, fmaf( P.x, W0c0.y, fmaf(P.w, W1c0.x, fmaf( P.z, W1c0.y, Bb.y))));
      float zr1 = fmaf(Q.x, W0c1.x, fmaf(-Q.y, W0c1.y, fmaf(Q.z, W1c1.x, fmaf(-Q.w, W1c1.y, Bb.z))));
      float zi1 = fmaf(Q.y, W0c1.x, fmaf( Q.x, W0c1.y, fmaf(Q.w, W1c1.x, fmaf( Q.z, W1c1.y, Bb.w))));
      float d2 = fmaxf(fmaf(zr1, zr1, zi1 * zi1), 1e-12f);
      float rn = __builtin_amdgcn_rsqf(d2);            // v_rsq_f32, ~1 ulp
      float w = fmaf(zr0, zr1, zi0 * zi1) * rn;
      if (fabsf(w) < 1e-12f) w = (w > 0.f) ? 1e-12f : ((w < 0.f) ? -1e-12f : 0.f);
      wf[b][k] = w;
      wfs16[((b * RANK + k) << 18) + p] = __float2half(w);  // streamed, coalesced
    }
  }
  // reduce gram[4][36] (upper-tri incl diag) + S[4][8] — exact f32 values
  int lane = t & 63, wv = t >> 6;
#pragma unroll
  for (int b = 0; b < BATCH; ++b) {
    int idx = b * 36;
#pragma unroll
    for (int r = 0; r < RANK; ++r)
#pragma unroll
      for (int s = r; s < RANK; ++s, ++idx) {
        float pr = dpp_sum64(wf[b][r] * wf[b][s]);
        if (lane == 63) gred[wv][idx] = pr;
      }
  }
#pragma unroll
  for (int b = 0; b < BATCH; ++b)
#pragma unroll
    for (int k = 0; k < RANK; ++k) {
      float pr = dpp_sum64(wf[b][k]);
      if (lane == 63) gred[wv][144 + b * 8 + k] = pr;
    }
  __syncthreads();
  if (t < NACC) {
    float s = gred[0][t] + gred[1][t] + gred[2][t] + gred[3][t];
    // 8-way replicated accumulators: same-address contention /8
    atomicAdd(ws + ACC_OFF + (blockIdx.x & (REP - 1)) * NACC + t, s);
  }
}

// ---------------- K3: analytic stats + output + noise ------------------------
__global__ __launch_bounds__(256) void k_out(const float* __restrict__ ws,
                                             float* __restrict__ out) {
  const float* xt = ws + XT_OFF;
  const __half* wfs16 = (const __half*)((const char*)ws + WFS_OFF * 4);
  __shared__ float G[NACC];                  // [0:144) gram, [144:176) S
  __shared__ float n1[32], Ml[256], vv[32], scl[32], ca[4], wrl[BATCH][9];
  __shared__ float in2[32], mnv[32], sdv[32];
  int t = threadIdx.x;
  if (t < NACC) {
    float s = 0.f;
#pragma unroll
    for (int rep = 0; rep < REP; ++rep) s += ws[ACC_OFF + rep * NACC + t];
    G[t] = s;
  }
  if (t >= 192 && t < 192 + BATCH) {         // wr softmax (per-batch thread)
    int b = t - 192;
    float raw[9];
#pragma unroll
    for (int j = 0; j < 9; ++j)
      raw[j] = xt[b * OUTF + 96 + j] * tanhf(xt[b * OUTF + 201 + j]);
    raw[8] += 0.35355339059327373f;          // 1/sqrt(8)
    double ss = 0.0;
    for (int j = 0; j < 9; ++j) ss += (double)raw[j] * (double)raw[j];
    float n = fmaxf((float)sqrt(ss), 1e-12f);
    float y[9]; float m = -1e30f;
    for (int j = 0; j < 9; ++j) { y[j] = raw[j] / n; m = fmaxf(m, y[j]); }
    float e[9]; double se = 0.0;
    for (int j = 0; j < 9; ++j) { e[j] = expf(y[j] - m); se += (double)e[j]; }
    for (int j = 0; j < 9; ++j) wrl[b][j] = e[j] / (float)se;
  }
  __syncthreads();
  if (t < 32) {
    int b = t >> 3, k = t & 7;
    int di = k * 8 - (k * (k - 1)) / 2;
    n1[t] = fmaxf(sqrtf(G[b * 36 + di]), 1e-12f);
  }
  __syncthreads();
  {
    int b = t >> 6, k = (t >> 3) & 7, s = t & 7;
    float m;
    if (k == s) {
      m = 1.0f / n1[b * 8 + k];
    } else {
      int r0 = k < s ? k : s, s0 = k < s ? s : k;
      int gi = r0 * 8 - (r0 * (r0 - 1)) / 2 + (s0 - r0);
      float simv = G[b * 36 + gi] / (n1[b * 8 + k] * n1[b * 8 + s]);
      m = -0.0050507627227610544f * simv / n1[b * 8 + s];  // (0.1/sqrt(8))/7
    }
    Ml[t] = m;
  }
  __syncthreads();
  if (t < 32) {
    int b = t >> 3, k = t & 7;
    // sum = M.S ; sumsq = (M G M^T)_kk — exact linear algebra of the 2nd pass
    float sum = 0.f, sq = 0.f;
#pragma unroll
    for (int s = 0; s < 8; ++s) {
      float ms = Ml[b * 64 + k * 8 + s];
      sum = fmaf(ms, G[144 + b * 8 + s], sum);
#pragma unroll
      for (int u = 0; u < 8; ++u) {
        int r0 = s < u ? s : u, s0 = s < u ? u : s;
        int gi = r0 * 8 - (r0 * (r0 - 1)) / 2 + (s0 - r0);
        sq = fmaf(ms * Ml[b * 64 + k * 8 + u], G[b * 36 + gi], sq);
      }
    }
    float n2 = fmaxf(sqrtf(fmaxf(sq, 0.f)), 1e-12f);
    float mean = sum / n2 * (1.0f / NPIX);
    float sy2 = sq / (n2 * n2);
    float var = (sy2 - (float)NPIX * mean * mean) * (1.0f / (float)(NPIX - 1));
    var = fmaxf(var, 0.f);
    float sd = fmaxf(sqrtf(var), 1e-12f);
    in2[t] = 1.f / n2; mnv[t] = mean; sdv[t] = sd;
  }
  __syncthreads();
  if (t < 32) {
    int b = t >> 3, s = t & 7;
    float acc = 0.f;
#pragma unroll
    for (int k = 0; k < 8; ++k)
      acc += wrl[b][k] * Ml[b * 64 + k * 8 + s] * in2[b * 8 + k];
    vv[t] = acc;
    scl[t] = wrl[b][s] * 0.01f * sdv[t];
  }
  if (t < BATCH) {
    float a = 0.f;
#pragma unroll
    for (int k = 0; k < 8; ++k) a += wrl[t][k] * 0.01f * mnv[t * 8 + k];
    ca[t] = a;
  }
  __syncthreads();

  int p = blockIdx.x * 256 + t;
  float o[4];
#pragma unroll
  for (int b = 0; b < 4; ++b) {
    float acc = ca[b];
#pragma unroll
    for (int s = 0; s < 8; ++s)
      acc = fmaf(vv[b * 8 + s], __half2float(wfs16[((b * RANK + s) << 18) + p]), acc);
    o[b] = acc;
  }
  // noise: flat j=(b*8+k)*NPIX+p over 2^23 elems; (j, j+2^22) share a threefry block
#pragma unroll
  for (int bk = 0; bk < 16; ++bk) {
    unsigned int i = ((unsigned int)bk << 18) + (unsigned int)p;
    unsigned int r0, r1;
    threefry2x32_pair(i, i + 0x400000u, &r0, &r1);
    int b2 = bk >> 3, k = bk & 7;
    o[b2]     += scl[b2 * 8 + k]       * fast_normal(r0);
    o[b2 + 2] += scl[(b2 + 2) * 8 + k] * fast_normal(r1);
  }
#pragma unroll
  for (int b = 0; b < 4; ++b) out[(b << 18) + p] = o[b];
}

extern "C" void kernel_launch(void* const* d_in, const int* in_sizes, int n_in,
                              void* d_out, int out_size, void* d_ws, size_t ws_size,
                              hipStream_t stream) {
  const float* x   = (const float*)d_in[0];
  const float* cw  = (const float*)d_in[1];
  const float* cb  = (const float*)d_in[2];
  const float* wts = (const float*)d_in[3];
  float* out = (float*)d_out;
  float* ws  = (float*)d_ws;

  hipMemsetAsync((char*)d_ws + ZERO_BYTE, 0, ZERO_LEN, stream);

  k_ctx <<<210,  256, 0, stream>>>(x, cw, cb, ws);
  k_wfs <<<1024, 256, 0, stream>>>(wts, ws);
  k_out <<<1024, 256, 0, stream>>>(ws, out);
}

// Round 9
// 141.883 us; speedup vs baseline: 2.1528x; 1.0163x over previous
//
#include <hip/hip_runtime.h>
#include <hip/hip_fp16.h>
#include <math.h>

#define NPIX 262144   // 512*512
#define BATCH 4
#define RANK 8
#define CTXD 512
#define OUTF 210

// ---- workspace layout (float offsets) ----
#define XT_OFF   0      // xt[4][210] (840 floats)
#define ACC_OFF  1024   // 8 replicas x 176 accumulators (gram[4][36], S[4][8])
#define REP      8
#define NACC     176
#define WFS_OFF  4096   // byte 16384: __half wfs[32][NPIX] rank-major = 16 MiB
#define ZERO_BYTE (ACC_OFF * 4)
#define ZERO_LEN  (REP * NACC * 4)

// ---------------- wave64 sum via DPP (result in lane 63) ---------------------
__device__ __forceinline__ float dpp_sum64(float x) {
  x += __int_as_float(__builtin_amdgcn_update_dpp(0, __float_as_int(x), 0x111, 0xf, 0xf, true)); // row_shr:1
  x += __int_as_float(__builtin_amdgcn_update_dpp(0, __float_as_int(x), 0x112, 0xf, 0xf, true)); // row_shr:2
  x += __int_as_float(__builtin_amdgcn_update_dpp(0, __float_as_int(x), 0x114, 0xf, 0xf, true)); // row_shr:4
  x += __int_as_float(__builtin_amdgcn_update_dpp(0, __float_as_int(x), 0x118, 0xf, 0xf, true)); // row_shr:8
  x += __int_as_float(__builtin_amdgcn_update_dpp(0, __float_as_int(x), 0x142, 0xf, 0xf, true)); // row_bcast:15
  x += __int_as_float(__builtin_amdgcn_update_dpp(0, __float_as_int(x), 0x143, 0xf, 0xf, true)); // row_bcast:31
  return x;
}

// ---------------- threefry2x32 (JAX original scheme, key=(0,42)) -------------
__device__ __forceinline__ void threefry2x32_pair(unsigned int x0, unsigned int x1,
                                                  unsigned int* o0, unsigned int* o1) {
  const unsigned int ks0 = 0u, ks1 = 42u, ks2 = 0x1BD11BF0u;
  x0 += ks0; x1 += ks1;
#define TF_R(rot) { x0 += x1; x1 = (x1 << rot) | (x1 >> (32 - rot)); x1 ^= x0; }
  TF_R(13) TF_R(15) TF_R(26) TF_R(6)
  x0 += ks1; x1 += ks2 + 1u;
  TF_R(17) TF_R(29) TF_R(16) TF_R(24)
  x0 += ks2; x1 += ks0 + 2u;
  TF_R(13) TF_R(15) TF_R(26) TF_R(6)
  x0 += ks0; x1 += ks1 + 3u;
  TF_R(17) TF_R(29) TF_R(16) TF_R(24)
  x0 += ks1; x1 += ks2 + 4u;
  TF_R(13) TF_R(15) TF_R(26) TF_R(6)
  x0 += ks2; x1 += ks0 + 5u;
#undef TF_R
  *o0 = x0; *o1 = x1;
}

// bits -> uniform(-1,1) -> sqrt(2)*erfinv (Giles poly, fast log path).
// Noise enters the output scaled by wr*0.01*std (~1e-10 here), so few-ulp is plenty.
__device__ __forceinline__ float fast_normal(unsigned int bits) {
  unsigned int fb = (bits >> 9) | 0x3f800000u;
  float f = __uint_as_float(fb) - 1.0f;                 // [0,1)
  const float lo = -0.99999994039535522461f;            // nextafter(-1,0) f32
  float u = f * 2.0f + lo;
  u = fmaxf(u, lo);
  float w = -__logf(fmaf(-u, u, 1.0f));                 // -log(1-u^2)
  float q1 = w - 2.5f;
  float p1 = 2.81022636e-08f;
  p1 = fmaf(p1, q1, 3.43273939e-07f);
  p1 = fmaf(p1, q1, -3.5233877e-06f);
  p1 = fmaf(p1, q1, -4.39150654e-06f);
  p1 = fmaf(p1, q1, 0.00021858087f);
  p1 = fmaf(p1, q1, -0.00125372503f);
  p1 = fmaf(p1, q1, -0.00417768164f);
  p1 = fmaf(p1, q1, 0.246640727f);
  p1 = fmaf(p1, q1, 1.50140941f);
  float q2 = sqrtf(w) - 3.0f;
  float p2 = -0.000200214257f;
  p2 = fmaf(p2, q2, 0.000100950558f);
  p2 = fmaf(p2, q2, 0.00134934322f);
  p2 = fmaf(p2, q2, -0.00367342844f);
  p2 = fmaf(p2, q2, 0.00573950773f);
  p2 = fmaf(p2, q2, -0.0076224613f);
  p2 = fmaf(p2, q2, 0.00943887047f);
  p2 = fmaf(p2, q2, 1.00167406f);
  p2 = fmaf(p2, q2, 2.83297682f);
  float pr = (w < 5.0f) ? p1 : p2;
  return 1.4142135623730951f * pr * u;
}

// ---------------- K1: ctx MLP — one 512-dot per wave, 840 waves --------------
__global__ __launch_bounds__(256) void k_ctx(const float* __restrict__ x,
                                             const float* __restrict__ cw,
                                             const float* __restrict__ cb,
                                             float* __restrict__ ws) {
  int lane = threadIdx.x & 63, wv = threadIdx.x >> 6;
  int row = blockIdx.x * 4 + wv;            // 0..839 (grid=210 exactly covers)
  int b = row / OUTF, i = row - b * OUTF;
  const float* wrow = cw + i * CTXD;
  const float* xr = x + b * CTXD;
  float acc = 0.f;
#pragma unroll
  for (int u = 0; u < CTXD; u += 64)
    acc = fmaf(wrow[u + lane], xr[u + lane], acc);
  acc = dpp_sum64(acc);
  if (lane == 63) ws[XT_OFF + row] = acc + cb[i];
}

// ---------------- K2: wf compute + fp16 store, Gram + per-rank sums ----------
// 2 px/thread (float4 weight loads, half2 stores), 128-thr x 1024 blocks.
// Gram DPP chains amortized over 2 pixels (register pre-accumulation).
// Stores streamed inside the loop — NO packing union (R6 spill trap).
__global__ __launch_bounds__(128) void k_wfs(const float* __restrict__ wts,
                                             float* __restrict__ ws) {
  __shared__ float4 mods[32][3];   // [b*8+k][0]=A0,B0  [1]=A1,B1  [2]=biases
  __shared__ float gred[2][NACC];
  const float* xt = ws + XT_OFF;
  __half2* wfs2 = (__half2*)((char*)ws + WFS_OFF * 4);
  int t = threadIdx.x;

  if (t < 96) {
    int bk = t / 3, part = t - bk * 3;
    int b = bk >> 3, k = bk & 7;
    const float* xb = xt + b * OUTF + 12 * k;
#define GATE(j) (xb[j] * tanhf(xb[105 + (j)]))
    float4 r;
    if (part < 2) {
      float c0 = GATE(2 * part) + 0.5f;
      float c1 = GATE(2 * part + 1);
      float s0 = GATE(8 + 2 * part) + 1.0f;
      float s1 = GATE(9 + 2 * part);
      float omc = 1.0f - c0;
      r.x = s0 * omc + s1 * c1;   // A_r
      r.y = s1 * omc - s0 * c1;   // A_i
      r.z = s0 * c0 - s1 * c1;    // B_r
      r.w = s1 * c0 + s0 * c1;    // B_i
    } else {
      r.x = GATE(4); r.y = GATE(5); r.z = GATE(6); r.w = GATE(7);
    }
#undef GATE
    mods[bk][part] = r;
  }
  __syncthreads();

  int tp = blockIdx.x * 128 + t;            // 0..131071, 2 adjacent pixels each
  const float4* w4 = (const float4*)wts;    // float4 = 2 complex px; 2^17 per page
  float wf[BATCH][RANK][2];
#pragma unroll
  for (int k = 0; k < RANK; ++k) {
    // ld[lerp][comp] = {px0.re, px0.im, px1.re, px1.im}
    float4 ld[2][2];
#pragma unroll
    for (int s = 0; s < 2; ++s)
#pragma unroll
      for (int comp = 0; comp < 2; ++comp)
        ld[s][comp] = w4[((k * 4 + s * 2 + comp) << 17) + tp];
#pragma unroll
    for (int b = 0; b < BATCH; ++b) {
      float4 P  = mods[b * 8 + k][0];
      float4 Q  = mods[b * 8 + k][1];
      float4 Bb = mods[b * 8 + k][2];
      __half2 st;
#pragma unroll
      for (int j = 0; j < 2; ++j) {
        float w0r = j ? ld[0][0].z : ld[0][0].x;
        float w0i = j ? ld[0][0].w : ld[0][0].y;
        float w1r = j ? ld[1][0].z : ld[1][0].x;
        float w1i = j ? ld[1][0].w : ld[1][0].y;
        float v0r = j ? ld[0][1].z : ld[0][1].x;
        float v0i = j ? ld[0][1].w : ld[0][1].y;
        float v1r = j ? ld[1][1].z : ld[1][1].x;
        float v1i = j ? ld[1][1].w : ld[1][1].y;
        float zr0 = fmaf(P.x, w0r, fmaf(-P.y, w0i, fmaf(P.z, w1r, fmaf(-P.w, w1i, Bb.x))));
        float zi0 = fmaf(P.y, w0r, fmaf( P.x, w0i, fmaf(P.w, w1r, fmaf( P.z, w1i, Bb.y))));
        float zr1 = fmaf(Q.x, v0r, fmaf(-Q.y, v0i, fmaf(Q.z, v1r, fmaf(-Q.w, v1i, Bb.z))));
        float zi1 = fmaf(Q.y, v0r, fmaf( Q.x, v0i, fmaf(Q.w, v1r, fmaf( Q.z, v1i, Bb.w))));
        float d2 = fmaxf(fmaf(zr1, zr1, zi1 * zi1), 1e-12f);
        float rn = __builtin_amdgcn_rsqf(d2);          // v_rsq_f32, ~1 ulp
        float w = fmaf(zr0, zr1, zi0 * zi1) * rn;
        if (fabsf(w) < 1e-12f) w = (w > 0.f) ? 1e-12f : ((w < 0.f) ? -1e-12f : 0.f);
        wf[b][k][j] = w;
        if (j) st.y = __float2half(w); else st.x = __float2half(w);
      }
      wfs2[((b * RANK + k) << 17) + tp] = st;  // 2 px, one 4B store, coalesced
    }
  }
  // reduce gram[4][36] (upper-tri incl diag) + S[4][8]; 2-px register pre-sum
  int lane = t & 63, wv = t >> 6;
#pragma unroll
  for (int b = 0; b < BATCH; ++b) {
    int idx = b * 36;
#pragma unroll
    for (int r = 0; r < RANK; ++r)
#pragma unroll
      for (int s = r; s < RANK; ++s, ++idx) {
        float pr = dpp_sum64(fmaf(wf[b][r][0], wf[b][s][0], wf[b][r][1] * wf[b][s][1]));
        if (lane == 63) gred[wv][idx] = pr;
      }
  }
#pragma unroll
  for (int b = 0; b < BATCH; ++b)
#pragma unroll
    for (int k = 0; k < RANK; ++k) {
      float pr = dpp_sum64(wf[b][k][0] + wf[b][k][1]);
      if (lane == 63) gred[wv][144 + b * 8 + k] = pr;
    }
  __syncthreads();
  // 128 threads < NACC=176 — MUST stride (R5 bug lesson)
  for (int i = t; i < NACC; i += 128) {
    float s = gred[0][i] + gred[1][i];
    // 8-way replicated accumulators: same-address contention /8
    atomicAdd(ws + ACC_OFF + (blockIdx.x & (REP - 1)) * NACC + i, s);
  }
}

// ---------------- K3: analytic stats + output + noise ------------------------
__global__ __launch_bounds__(256) void k_out(const float* __restrict__ ws,
                                             float* __restrict__ out) {
  const float* xt = ws + XT_OFF;
  const __half* wfs16 = (const __half*)((const char*)ws + WFS_OFF * 4);
  __shared__ float G[NACC];                  // [0:144) gram, [144:176) S
  __shared__ float n1[32], Ml[256], vv[32], scl[32], ca[4], wrl[BATCH][9];
  __shared__ float in2[32], mnv[32], sdv[32];
  int t = threadIdx.x;
  if (t < NACC) {
    float s = 0.f;
#pragma unroll
    for (int rep = 0; rep < REP; ++rep) s += ws[ACC_OFF + rep * NACC + t];
    G[t] = s;
  }
  if (t >= 192 && t < 192 + BATCH) {         // wr softmax (per-batch thread)
    int b = t - 192;
    float raw[9];
#pragma unroll
    for (int j = 0; j < 9; ++j)
      raw[j] = xt[b * OUTF + 96 + j] * tanhf(xt[b * OUTF + 201 + j]);
    raw[8] += 0.35355339059327373f;          // 1/sqrt(8)
    double ss = 0.0;
    for (int j = 0; j < 9; ++j) ss += (double)raw[j] * (double)raw[j];
    float n = fmaxf((float)sqrt(ss), 1e-12f);
    float y[9]; float m = -1e30f;
    for (int j = 0; j < 9; ++j) { y[j] = raw[j] / n; m = fmaxf(m, y[j]); }
    float e[9]; double se = 0.0;
    for (int j = 0; j < 9; ++j) { e[j] = expf(y[j] - m); se += (double)e[j]; }
    for (int j = 0; j < 9; ++j) wrl[b][j] = e[j] / (float)se;
  }
  __syncthreads();
  if (t < 32) {
    int b = t >> 3, k = t & 7;
    int di = k * 8 - (k * (k - 1)) / 2;
    n1[t] = fmaxf(sqrtf(G[b * 36 + di]), 1e-12f);
  }
  __syncthreads();
  {
    int b = t >> 6, k = (t >> 3) & 7, s = t & 7;
    float m;
    if (k == s) {
      m = 1.0f / n1[b * 8 + k];
    } else {
      int r0 = k < s ? k : s, s0 = k < s ? s : k;
      int gi = r0 * 8 - (r0 * (r0 - 1)) / 2 + (s0 - r0);
      float simv = G[b * 36 + gi] / (n1[b * 8 + k] * n1[b * 8 + s]);
      m = -0.0050507627227610544f * simv / n1[b * 8 + s];  // (0.1/sqrt(8))/7
    }
    Ml[t] = m;
  }
  __syncthreads();
  if (t < 32) {
    int b = t >> 3, k = t & 7;
    // sum = M.S ; sumsq = (M G M^T)_kk — exact linear algebra of the 2nd pass
    float sum = 0.f, sq = 0.f;
#pragma unroll
    for (int s = 0; s < 8; ++s) {
      float ms = Ml[b * 64 + k * 8 + s];
      sum = fmaf(ms, G[144 + b * 8 + s], sum);
#pragma unroll
      for (int u = 0; u < 8; ++u) {
        int r0 = s < u ? s : u, s0 = s < u ? u : s;
        int gi = r0 * 8 - (r0 * (r0 - 1)) / 2 + (s0 - r0);
        sq = fmaf(ms * Ml[b * 64 + k * 8 + u], G[b * 36 + gi], sq);
      }
    }
    float n2 = fmaxf(sqrtf(fmaxf(sq, 0.f)), 1e-12f);
    float mean = sum / n2 * (1.0f / NPIX);
    float sy2 = sq / (n2 * n2);
    float var = (sy2 - (float)NPIX * mean * mean) * (1.0f / (float)(NPIX - 1));
    var = fmaxf(var, 0.f);
    float sd = fmaxf(sqrtf(var), 1e-12f);
    in2[t] = 1.f / n2; mnv[t] = mean; sdv[t] = sd;
  }
  __syncthreads();
  if (t < 32) {
    int b = t >> 3, s = t & 7;
    float acc = 0.f;
#pragma unroll
    for (int k = 0; k < 8; ++k)
      acc += wrl[b][k] * Ml[b * 64 + k * 8 + s] * in2[b * 8 + k];
    vv[t] = acc;
    scl[t] = wrl[b][s] * 0.01f * sdv[t];
  }
  if (t < BATCH) {
    float a = 0.f;
#pragma unroll
    for (int k = 0; k < 8; ++k) a += wrl[t][k] * 0.01f * mnv[t * 8 + k];
    ca[t] = a;
  }
  __syncthreads();

  int p = blockIdx.x * 256 + t;
  float o[4];
#pragma unroll
  for (int b = 0; b < 4; ++b) {
    float acc = ca[b];
#pragma unroll
    for (int s = 0; s < 8; ++s)
      acc = fmaf(vv[b * 8 + s], __half2float(wfs16[((b * RANK + s) << 18) + p]), acc);
    o[b] = acc;
  }
  // noise: flat j=(b*8+k)*NPIX+p over 2^23 elems; (j, j+2^22) share a threefry block
#pragma unroll
  for (int bk = 0; bk < 16; ++bk) {
    unsigned int i = ((unsigned int)bk << 18) + (unsigned int)p;
    unsigned int r0, r1;
    threefry2x32_pair(i, i + 0x400000u, &r0, &r1);
    int b2 = bk >> 3, k = bk & 7;
    o[b2]     += scl[b2 * 8 + k]       * fast_normal(r0);
    o[b2 + 2] += scl[(b2 + 2) * 8 + k] * fast_normal(r1);
  }
#pragma unroll
  for (int b = 0; b < 4; ++b) out[(b << 18) + p] = o[b];
}

extern "C" void kernel_launch(void* const* d_in, const int* in_sizes, int n_in,
                              void* d_out, int out_size, void* d_ws, size_t ws_size,
                              hipStream_t stream) {
  const float* x   = (const float*)d_in[0];
  const float* cw  = (const float*)d_in[1];
  const float* cb  = (const float*)d_in[2];
  const float* wts = (const float*)d_in[3];
  float* out = (float*)d_out;
  float* ws  = (float*)d_ws;

  hipMemsetAsync((char*)d_ws + ZERO_BYTE, 0, ZERO_LEN, stream);

  k_ctx <<<210,  256, 0, stream>>>(x, cw, cb, ws);
  k_wfs <<<1024, 128, 0, stream>>>(wts, ws);
  k_out <<<1024, 256, 0, stream>>>(ws, out);
}

// Round 10
// 137.467 us; speedup vs baseline: 2.2220x; 1.0321x over previous
//
#include <hip/hip_runtime.h>
#include <hip/hip_fp16.h>
#include <math.h>

#define NPIX 262144   // 512*512
#define BATCH 4
#define RANK 8
#define CTXD 512
#define OUTF 210

// ---- workspace layout (float offsets) ----
#define XT_OFF   0      // xt[4][210] (840 floats)
#define ACC_OFF  1024   // 8 replicas x 176 accumulators (gram[4][36], S[4][8])
#define REP      8
#define NACC     176
#define WFS_OFF  4096   // byte 16384: __half wfs[32][NPIX] rank-major = 16 MiB

// ---------------- wave64 sum via DPP (result in lane 63) ---------------------
__device__ __forceinline__ float dpp_sum64(float x) {
  x += __int_as_float(__builtin_amdgcn_update_dpp(0, __float_as_int(x), 0x111, 0xf, 0xf, true)); // row_shr:1
  x += __int_as_float(__builtin_amdgcn_update_dpp(0, __float_as_int(x), 0x112, 0xf, 0xf, true)); // row_shr:2
  x += __int_as_float(__builtin_amdgcn_update_dpp(0, __float_as_int(x), 0x114, 0xf, 0xf, true)); // row_shr:4
  x += __int_as_float(__builtin_amdgcn_update_dpp(0, __float_as_int(x), 0x118, 0xf, 0xf, true)); // row_shr:8
  x += __int_as_float(__builtin_amdgcn_update_dpp(0, __float_as_int(x), 0x142, 0xf, 0xf, true)); // row_bcast:15
  x += __int_as_float(__builtin_amdgcn_update_dpp(0, __float_as_int(x), 0x143, 0xf, 0xf, true)); // row_bcast:31
  return x;
}

// ---------------- threefry2x32 (JAX original scheme, key=(0,42)) -------------
__device__ __forceinline__ void threefry2x32_pair(unsigned int x0, unsigned int x1,
                                                  unsigned int* o0, unsigned int* o1) {
  const unsigned int ks0 = 0u, ks1 = 42u, ks2 = 0x1BD11BF0u;
  x0 += ks0; x1 += ks1;
#define TF_R(rot) { x0 += x1; x1 = (x1 << rot) | (x1 >> (32 - rot)); x1 ^= x0; }
  TF_R(13) TF_R(15) TF_R(26) TF_R(6)
  x0 += ks1; x1 += ks2 + 1u;
  TF_R(17) TF_R(29) TF_R(16) TF_R(24)
  x0 += ks2; x1 += ks0 + 2u;
  TF_R(13) TF_R(15) TF_R(26) TF_R(6)
  x0 += ks0; x1 += ks1 + 3u;
  TF_R(17) TF_R(29) TF_R(16) TF_R(24)
  x0 += ks1; x1 += ks2 + 4u;
  TF_R(13) TF_R(15) TF_R(26) TF_R(6)
  x0 += ks2; x1 += ks0 + 5u;
#undef TF_R
  *o0 = x0; *o1 = x1;
}

// bits -> uniform(-1,1) -> sqrt(2)*erfinv. Giles polys TRUNCATED 9->5 terms:
// abs error <= 2.2e-3 (w<5) / 7.5e-3 (w>=5) in the normal sample; noise is
// scaled by ~2e-6, so worst-case output perturbation ~1.4e-7 << 1.05e-5 budget.
__device__ __forceinline__ float fast_normal(unsigned int bits) {
  unsigned int fb = (bits >> 9) | 0x3f800000u;
  float f = __uint_as_float(fb) - 1.0f;                 // [0,1)
  const float lo = -0.99999994039535522461f;            // nextafter(-1,0) f32
  float u = f * 2.0f + lo;
  u = fmaxf(u, lo);
  float w = -__logf(fmaf(-u, u, 1.0f));                 // -log(1-u^2)
  float q1 = w - 2.5f;
  float p1 = 0.00021858087f;
  p1 = fmaf(p1, q1, -0.00125372503f);
  p1 = fmaf(p1, q1, -0.00417768164f);
  p1 = fmaf(p1, q1, 0.246640727f);
  p1 = fmaf(p1, q1, 1.50140941f);
  float q2 = sqrtf(w) - 3.0f;
  float p2 = 0.00573950773f;
  p2 = fmaf(p2, q2, -0.0076224613f);
  p2 = fmaf(p2, q2, 0.00943887047f);
  p2 = fmaf(p2, q2, 1.00167406f);
  p2 = fmaf(p2, q2, 2.83297682f);
  float pr = (w < 5.0f) ? p1 : p2;
  return 1.4142135623730951f * pr * u;
}

// ---------------- K1: ctx MLP + accumulator zeroing --------------------------
__global__ __launch_bounds__(256) void k_ctx(const float* __restrict__ x,
                                             const float* __restrict__ cw,
                                             const float* __restrict__ cb,
                                             float* __restrict__ ws) {
  // zero the REP*NACC atomic accumulators (replaces a separate memset dispatch;
  // kernel boundary orders this before k_wfs's atomics)
  int gi = blockIdx.x * 256 + threadIdx.x;
  if (gi < REP * NACC) ws[ACC_OFF + gi] = 0.f;

  int lane = threadIdx.x & 63, wv = threadIdx.x >> 6;
  int row = blockIdx.x * 4 + wv;            // 0..839 (grid=210 exactly covers)
  int b = row / OUTF, i = row - b * OUTF;
  const float* wrow = cw + i * CTXD;
  const float* xr = x + b * CTXD;
  float acc = 0.f;
#pragma unroll
  for (int u = 0; u < CTXD; u += 64)
    acc = fmaf(wrow[u + lane], xr[u + lane], acc);
  acc = dpp_sum64(acc);
  if (lane == 63) ws[XT_OFF + row] = acc + cb[i];
}

// ---------------- K2: wf compute + fp16 store, Gram + per-rank sums ----------
// 2 px/thread (float4 weight loads, half2 stores), 128-thr x 1024 blocks.
// Gram DPP chains amortized over 2 pixels (register pre-accumulation).
// Stores streamed inside the loop — NO packing union (R6 spill trap).
// The _stable +-1e-12 clamp is dropped: fp16 flushes it to 0 anyway and its
// gram contribution is <=1e-19 relative.
__global__ __launch_bounds__(128) void k_wfs(const float* __restrict__ wts,
                                             float* __restrict__ ws) {
  __shared__ float4 mods[32][3];   // [b*8+k][0]=A0,B0  [1]=A1,B1  [2]=biases
  __shared__ float gred[2][NACC];
  const float* xt = ws + XT_OFF;
  __half2* wfs2 = (__half2*)((char*)ws + WFS_OFF * 4);
  int t = threadIdx.x;

  if (t < 96) {
    int bk = t / 3, part = t - bk * 3;
    int b = bk >> 3, k = bk & 7;
    const float* xb = xt + b * OUTF + 12 * k;
#define GATE(j) (xb[j] * tanhf(xb[105 + (j)]))
    float4 r;
    if (part < 2) {
      float c0 = GATE(2 * part) + 0.5f;
      float c1 = GATE(2 * part + 1);
      float s0 = GATE(8 + 2 * part) + 1.0f;
      float s1 = GATE(9 + 2 * part);
      float omc = 1.0f - c0;
      r.x = s0 * omc + s1 * c1;   // A_r
      r.y = s1 * omc - s0 * c1;   // A_i
      r.z = s0 * c0 - s1 * c1;    // B_r
      r.w = s1 * c0 + s0 * c1;    // B_i
    } else {
      r.x = GATE(4); r.y = GATE(5); r.z = GATE(6); r.w = GATE(7);
    }
#undef GATE
    mods[bk][part] = r;
  }
  __syncthreads();

  int tp = blockIdx.x * 128 + t;            // 0..131071, 2 adjacent pixels each
  const float4* w4 = (const float4*)wts;    // float4 = 2 complex px; 2^17 per page
  float wf[BATCH][RANK][2];
#pragma unroll
  for (int k = 0; k < RANK; ++k) {
    // ld[lerp][comp] = {px0.re, px0.im, px1.re, px1.im}
    float4 ld[2][2];
#pragma unroll
    for (int s = 0; s < 2; ++s)
#pragma unroll
      for (int comp = 0; comp < 2; ++comp)
        ld[s][comp] = w4[((k * 4 + s * 2 + comp) << 17) + tp];
#pragma unroll
    for (int b = 0; b < BATCH; ++b) {
      float4 P  = mods[b * 8 + k][0];
      float4 Q  = mods[b * 8 + k][1];
      float4 Bb = mods[b * 8 + k][2];
      __half2 st;
#pragma unroll
      for (int j = 0; j < 2; ++j) {
        float w0r = j ? ld[0][0].z : ld[0][0].x;
        float w0i = j ? ld[0][0].w : ld[0][0].y;
        float w1r = j ? ld[1][0].z : ld[1][0].x;
        float w1i = j ? ld[1][0].w : ld[1][0].y;
        float v0r = j ? ld[0][1].z : ld[0][1].x;
        float v0i = j ? ld[0][1].w : ld[0][1].y;
        float v1r = j ? ld[1][1].z : ld[1][1].x;
        float v1i = j ? ld[1][1].w : ld[1][1].y;
        float zr0 = fmaf(P.x, w0r, fmaf(-P.y, w0i, fmaf(P.z, w1r, fmaf(-P.w, w1i, Bb.x))));
        float zi0 = fmaf(P.y, w0r, fmaf( P.x, w0i, fmaf(P.w, w1r, fmaf( P.z, w1i, Bb.y))));
        float zr1 = fmaf(Q.x, v0r, fmaf(-Q.y, v0i, fmaf(Q.z, v1r, fmaf(-Q.w, v1i, Bb.z))));
        float zi1 = fmaf(Q.y, v0r, fmaf( Q.x, v0i, fmaf(Q.w, v1r, fmaf( Q.z, v1i, Bb.w))));
        float d2 = fmaxf(fmaf(zr1, zr1, zi1 * zi1), 1e-12f);
        float rn = __builtin_amdgcn_rsqf(d2);          // v_rsq_f32, ~1 ulp
        float w = fmaf(zr0, zr1, zi0 * zi1) * rn;
        wf[b][k][j] = w;
        if (j) st.y = __float2half(w); else st.x = __float2half(w);
      }
      wfs2[((b * RANK + k) << 17) + tp] = st;  // 2 px, one 4B store, coalesced
    }
  }
  // reduce gram[4][36] (upper-tri incl diag) + S[4][8]; 2-px register pre-sum
  int lane = t & 63, wv = t >> 6;
#pragma unroll
  for (int b = 0; b < BATCH; ++b) {
    int idx = b * 36;
#pragma unroll
    for (int r = 0; r < RANK; ++r)
#pragma unroll
      for (int s = r; s < RANK; ++s, ++idx) {
        float pr = dpp_sum64(fmaf(wf[b][r][0], wf[b][s][0], wf[b][r][1] * wf[b][s][1]));
        if (lane == 63) gred[wv][idx] = pr;
      }
  }
#pragma unroll
  for (int b = 0; b < BATCH; ++b)
#pragma unroll
    for (int k = 0; k < RANK; ++k) {
      float pr = dpp_sum64(wf[b][k][0] + wf[b][k][1]);
      if (lane == 63) gred[wv][144 + b * 8 + k] = pr;
    }
  __syncthreads();
  // 128 threads < NACC=176 — MUST stride (R5 bug lesson)
  for (int i = t; i < NACC; i += 128) {
    float s = gred[0][i] + gred[1][i];
    // 8-way replicated accumulators: same-address contention /8
    atomicAdd(ws + ACC_OFF + (blockIdx.x & (REP - 1)) * NACC + i, s);
  }
}

// ---------------- K3: analytic stats + output + noise ------------------------
__global__ __launch_bounds__(256) void k_out(const float* __restrict__ ws,
                                             float* __restrict__ out) {
  const float* xt = ws + XT_OFF;
  const __half* wfs16 = (const __half*)((const char*)ws + WFS_OFF * 4);
  __shared__ float G[NACC];                  // [0:144) gram, [144:176) S
  __shared__ float n1[32], Ml[256], vv[32], scl[32], ca[4], wrl[BATCH][9];
  __shared__ float in2[32], mnv[32], sdv[32];
  int t = threadIdx.x;
  if (t < NACC) {
    float s = 0.f;
#pragma unroll
    for (int rep = 0; rep < REP; ++rep) s += ws[ACC_OFF + rep * NACC + t];
    G[t] = s;
  }
  if (t >= 192 && t < 192 + BATCH) {         // wr softmax (per-batch thread)
    int b = t - 192;
    float raw[9];
#pragma unroll
    for (int j = 0; j < 9; ++j)
      raw[j] = xt[b * OUTF + 96 + j] * tanhf(xt[b * OUTF + 201 + j]);
    raw[8] += 0.35355339059327373f;          // 1/sqrt(8)
    double ss = 0.0;
    for (int j = 0; j < 9; ++j) ss += (double)raw[j] * (double)raw[j];
    float n = fmaxf((float)sqrt(ss), 1e-12f);
    float y[9]; float m = -1e30f;
    for (int j = 0; j < 9; ++j) { y[j] = raw[j] / n; m = fmaxf(m, y[j]); }
    float e[9]; double se = 0.0;
    for (int j = 0; j < 9; ++j) { e[j] = expf(y[j] - m); se += (double)e[j]; }
    for (int j = 0; j < 9; ++j) wrl[b][j] = e[j] / (float)se;
  }
  __syncthreads();
  if (t < 32) {
    int b = t >> 3, k = t & 7;
    int di = k * 8 - (k * (k - 1)) / 2;
    n1[t] = fmaxf(sqrtf(G[b * 36 + di]), 1e-12f);
  }
  __syncthreads();
  {
    int b = t >> 6, k = (t >> 3) & 7, s = t & 7;
    float m;
    if (k == s) {
      m = 1.0f / n1[b * 8 + k];
    } else {
      int r0 = k < s ? k : s, s0 = k < s ? s : k;
      int gi = r0 * 8 - (r0 * (r0 - 1)) / 2 + (s0 - r0);
      float simv = G[b * 36 + gi] / (n1[b * 8 + k] * n1[b * 8 + s]);
      m = -0.0050507627227610544f * simv / n1[b * 8 + s];  // (0.1/sqrt(8))/7
    }
    Ml[t] = m;
  }
  __syncthreads();
  if (t < 32) {
    int b = t >> 3, k = t & 7;
    // sum = M.S ; sumsq = (M G M^T)_kk — exact linear algebra of the 2nd pass
    float sum = 0.f, sq = 0.f;
#pragma unroll
    for (int s = 0; s < 8; ++s) {
      float ms = Ml[b * 64 + k * 8 + s];
      sum = fmaf(ms, G[144 + b * 8 + s], sum);
#pragma unroll
      for (int u = 0; u < 8; ++u) {
        int r0 = s < u ? s : u, s0 = s < u ? u : s;
        int gi = r0 * 8 - (r0 * (r0 - 1)) / 2 + (s0 - r0);
        sq = fmaf(ms * Ml[b * 64 + k * 8 + u], G[b * 36 + gi], sq);
      }
    }
    float n2 = fmaxf(sqrtf(fmaxf(sq, 0.f)), 1e-12f);
    float mean = sum / n2 * (1.0f / NPIX);
    float sy2 = sq / (n2 * n2);
    float var = (sy2 - (float)NPIX * mean * mean) * (1.0f / (float)(NPIX - 1));
    var = fmaxf(var, 0.f);
    float sd = fmaxf(sqrtf(var), 1e-12f);
    in2[t] = 1.f / n2; mnv[t] = mean; sdv[t] = sd;
  }
  __syncthreads();
  if (t < 32) {
    int b = t >> 3, s = t & 7;
    float acc = 0.f;
#pragma unroll
    for (int k = 0; k < 8; ++k)
      acc += wrl[b][k] * Ml[b * 64 + k * 8 + s] * in2[b * 8 + k];
    vv[t] = acc;
    scl[t] = wrl[b][s] * 0.01f * sdv[t];
  }
  if (t < BATCH) {
    float a = 0.f;
#pragma unroll
    for (int k = 0; k < 8; ++k) a += wrl[t][k] * 0.01f * mnv[t * 8 + k];
    ca[t] = a;
  }
  __syncthreads();

  int p = blockIdx.x * 256 + t;
  float o[4];
#pragma unroll
  for (int b = 0; b < 4; ++b) {
    float acc = ca[b];
#pragma unroll
    for (int s = 0; s < 8; ++s)
      acc = fmaf(vv[b * 8 + s], __half2float(wfs16[((b * RANK + s) << 18) + p]), acc);
    o[b] = acc;
  }
  // noise: flat j=(b*8+k)*NPIX+p over 2^23 elems; (j, j+2^22) share a threefry block
#pragma unroll
  for (int bk = 0; bk < 16; ++bk) {
    unsigned int i = ((unsigned int)bk << 18) + (unsigned int)p;
    unsigned int r0, r1;
    threefry2x32_pair(i, i + 0x400000u, &r0, &r1);
    int b2 = bk >> 3, k = bk & 7;
    o[b2]     += scl[b2 * 8 + k]       * fast_normal(r0);
    o[b2 + 2] += scl[(b2 + 2) * 8 + k] * fast_normal(r1);
  }
#pragma unroll
  for (int b = 0; b < 4; ++b) out[(b << 18) + p] = o[b];
}

extern "C" void kernel_launch(void* const* d_in, const int* in_sizes, int n_in,
                              void* d_out, int out_size, void* d_ws, size_t ws_size,
                              hipStream_t stream) {
  const float* x   = (const float*)d_in[0];
  const float* cw  = (const float*)d_in[1];
  const float* cb  = (const float*)d_in[2];
  const float* wts = (const float*)d_in[3];
  float* out = (float*)d_out;
  float* ws  = (float*)d_ws;

  k_ctx <<<210,  256, 0, stream>>>(x, cw, cb, ws);   // also zeroes accumulators
  k_wfs <<<1024, 128, 0, stream>>>(wts, ws);
  k_out <<<1024, 256, 0, stream>>>(ws, out);
}